// Round 4
// baseline (1232.048 us; speedup 1.0000x reference)
//
#include <hip/hip_runtime.h>

#define NUSERS 100000
#define NITEMS 50000
#define NNODES (NUSERS + NITEMS)
#define DIM 64
#define NEDGE 2000000
#define NI4 (NNODES / 4)            // 37500 int4 count-groups
#define SCAN_B ((NI4 + 255) / 256)  // 147 blocks

// ---------------------------------------------------------------------------
// init: buf0 = concat(emb_users, emb_items); also write the two
// pass-through output copies. float4 per thread.
// ---------------------------------------------------------------------------
__global__ void init_kernel(const float* __restrict__ eu, const float* __restrict__ eit,
                            float* __restrict__ buf0, float* __restrict__ out) {
    long i = (long)blockIdx.x * blockDim.x + threadIdx.x;      // float4 index
    const long total = (long)NNODES * DIM / 4;
    if (i >= total) return;
    const long ue = (long)NUSERS * DIM / 4;
    float4 v;
    if (i < ue) {
        v = ((const float4*)eu)[i];
        ((float4*)(out + (long)NUSERS * DIM))[i] = v;                          // users copy
    } else {
        long j = i - ue;
        v = ((const float4*)eit)[j];
        ((float4*)(out + (long)2 * NUSERS * DIM + (long)NITEMS * DIM))[j] = v; // items copy
    }
    ((float4*)buf0)[i] = v;
}

// ---------------------------------------------------------------------------
// CSR build step 1: histogram of dst. counts must be pre-zeroed.
// ---------------------------------------------------------------------------
__global__ void hist_kernel(const int* __restrict__ eidx, int* __restrict__ counts) {
    int e = blockIdx.x * blockDim.x + threadIdx.x;
    if (e < NEDGE) atomicAdd(&counts[eidx[NEDGE + e]], 1);
}

// ---------------------------------------------------------------------------
// CSR build step 2a: per-block sums (1024 counts per block via int4).
// ---------------------------------------------------------------------------
__global__ void blk_sum_kernel(const int* __restrict__ counts, int* __restrict__ blk_sums) {
    __shared__ int lds[256];
    int t = threadIdx.x;
    int i4 = blockIdx.x * 256 + t;
    int s = 0;
    if (i4 < NI4) {
        int4 c = ((const int4*)counts)[i4];
        s = c.x + c.y + c.z + c.w;
    }
    lds[t] = s;
    __syncthreads();
    for (int d = 128; d > 0; d >>= 1) {
        if (t < d) lds[t] += lds[t + d];
        __syncthreads();
    }
    if (t == 0) blk_sums[blockIdx.x] = lds[0];
}

// ---------------------------------------------------------------------------
// CSR build step 2b: exclusive scan of the SCAN_B block sums (single block).
// ---------------------------------------------------------------------------
__global__ void blk_scan_kernel(const int* __restrict__ blk_sums, int* __restrict__ blk_off) {
    __shared__ int lds[256];
    int t = threadIdx.x;
    int v = (t < SCAN_B) ? blk_sums[t] : 0;
    lds[t] = v;
    __syncthreads();
    for (int d = 1; d < 256; d <<= 1) {
        int u = (t >= d) ? lds[t - d] : 0;
        __syncthreads();
        lds[t] += u;
        __syncthreads();
    }
    if (t < SCAN_B) blk_off[t] = lds[t] - v;   // exclusive
}

// ---------------------------------------------------------------------------
// CSR build step 2c: local exclusive scan + block offset -> row_start, cursor.
// ---------------------------------------------------------------------------
__global__ void scan_apply_kernel(const int* __restrict__ counts, const int* __restrict__ blk_off,
                                  int* __restrict__ row_start, int* __restrict__ cursor) {
    __shared__ int lds[256];
    int t = threadIdx.x;
    int i4 = blockIdx.x * 256 + t;
    int4 c = make_int4(0, 0, 0, 0);
    if (i4 < NI4) c = ((const int4*)counts)[i4];
    int tsum = c.x + c.y + c.z + c.w;
    lds[t] = tsum;
    __syncthreads();
    for (int d = 1; d < 256; d <<= 1) {
        int u = (t >= d) ? lds[t - d] : 0;
        __syncthreads();
        lds[t] += u;
        __syncthreads();
    }
    if (i4 < NI4) {
        int base = blk_off[blockIdx.x] + lds[t] - tsum;   // exclusive across chunk
        int4 r;
        r.x = base;
        r.y = base + c.x;
        r.z = r.y + c.y;
        r.w = r.z + c.z;
        ((int4*)row_start)[i4] = r;
        ((int4*)cursor)[i4] = r;
    }
    if (blockIdx.x == 0 && t == 0) row_start[NNODES] = NEDGE;
}

// ---------------------------------------------------------------------------
// CSR build step 3: bucket edges by dst.
// ---------------------------------------------------------------------------
__global__ void fill_kernel(const int* __restrict__ eidx, const float* __restrict__ ew,
                            int* __restrict__ cursor, int* __restrict__ src_sorted,
                            float* __restrict__ w_sorted) {
    int e = blockIdx.x * blockDim.x + threadIdx.x;
    if (e >= NEDGE) return;
    int d = eidx[NEDGE + e];
    int pos = atomicAdd(&cursor[d], 1);
    src_sorted[pos] = eidx[e];
    w_sorted[pos] = ew[e];
}

// ---------------------------------------------------------------------------
// pull: one wave per dst node, lane = dim. No atomics; fused ReLU.
// ---------------------------------------------------------------------------
__global__ void pull_kernel(const int* __restrict__ row_start, const int* __restrict__ src_sorted,
                            const float* __restrict__ w_sorted, const float* __restrict__ in_emb,
                            float* __restrict__ out_emb) {
    int lane = threadIdx.x & 63;
    int n = (int)((blockIdx.x * (long)blockDim.x + threadIdx.x) >> 6);  // node = wave id
    if (n >= NNODES) return;
    int b = row_start[n];
    int e2 = row_start[n + 1];
    float s = 0.f;
    int i = b;
    for (; i + 1 < e2; i += 2) {
        int s0 = src_sorted[i], s1 = src_sorted[i + 1];
        float w0 = w_sorted[i], w1 = w_sorted[i + 1];
        float v0 = in_emb[(long)s0 * DIM + lane];
        float v1 = in_emb[(long)s1 * DIM + lane];
        s = fmaf(w0, v0, s);
        s = fmaf(w1, v1, s);
    }
    if (i < e2) {
        int s0 = src_sorted[i];
        float w0 = w_sorted[i];
        s = fmaf(w0, in_emb[(long)s0 * DIM + lane], s);
    }
    out_emb[(long)n * DIM + lane] = fmaxf(s, 0.f);
}

// ---------------------------------------------------------------------------
// epilogue: a = e0 + e1 + e2 (per row); out[i][j] = (a/3) . W[j][:] + b[j]
// Lane j holds W row j in 64 VGPRs. Row values broadcast via same-address
// float4 loads (HW broadcast). Two independent FMA chains for ILP.
// ---------------------------------------------------------------------------
__global__ __launch_bounds__(256, 4)
void final_kernel(const float* __restrict__ e0, const float* __restrict__ e1,
                  const float* __restrict__ e2, const float* __restrict__ W,
                  const float* __restrict__ bias, float* __restrict__ out) {
    int lane = threadIdx.x & 63;
    int wid  = (int)(((long)blockIdx.x * blockDim.x + threadIdx.x) >> 6);
    int nw   = (int)(((long)gridDim.x * blockDim.x) >> 6);
    float wreg[64];
#pragma unroll
    for (int k = 0; k < 16; ++k) {
        float4 wv = ((const float4*)(W + (long)lane * 64))[k];
        wreg[4 * k + 0] = wv.x; wreg[4 * k + 1] = wv.y;
        wreg[4 * k + 2] = wv.z; wreg[4 * k + 3] = wv.w;
    }
    float bj = bias[lane];
    for (int i = wid; i < NNODES; i += nw) {
        const float4* a0 = (const float4*)(e0 + (long)i * DIM);
        const float4* a1 = (const float4*)(e1 + (long)i * DIM);
        const float4* a2 = (const float4*)(e2 + (long)i * DIM);
        float s0 = 0.f, s1 = 0.f;
#pragma unroll
        for (int k = 0; k < 16; ++k) {
            float4 v0 = a0[k], v1 = a1[k], v2 = a2[k];
            float ax = v0.x + v1.x + v2.x;
            float ay = v0.y + v1.y + v2.y;
            float az = v0.z + v1.z + v2.z;
            float aw = v0.w + v1.w + v2.w;
            s0 = fmaf(ax, wreg[4 * k + 0], s0);
            s1 = fmaf(ay, wreg[4 * k + 1], s1);
            s0 = fmaf(az, wreg[4 * k + 2], s0);
            s1 = fmaf(aw, wreg[4 * k + 3], s1);
        }
        float val = fmaf(s0 + s1, (1.0f / 3.0f), bj);
        long o = (i < NUSERS) ? (long)i * DIM
                              : (long)2 * NUSERS * DIM + (long)(i - NUSERS) * DIM;
        out[o + lane] = val;
    }
}

extern "C" void kernel_launch(void* const* d_in, const int* in_sizes, int n_in,
                              void* d_out, int out_size, void* d_ws, size_t ws_size,
                              hipStream_t stream) {
    const int*   eidx = (const int*)d_in[0];     // (2, E) int
    const float* ew   = (const float*)d_in[1];   // (E,)
    const float* eu   = (const float*)d_in[2];   // (NUSERS, 64)
    const float* eit  = (const float*)d_in[3];   // (NITEMS, 64)
    const float* W    = (const float*)d_in[4];   // (64, 64)
    const float* bias = (const float*)d_in[5];   // (64,)
    float* out = (float*)d_out;

    const size_t nfeat = (size_t)NNODES * DIM;   // 9.6M floats
    float* buf0 = (float*)d_ws;                  // emb_0 (input concat)
    float* buf1 = buf0 + nfeat;                  // emb_1
    float* buf2 = buf1 + nfeat;                  // emb_2
    int*   counts     = (int*)(buf2 + nfeat);
    int*   row_start  = counts + NNODES;         // NNODES+1 entries
    int*   cursor     = row_start + NNODES + 1;
    int*   blk_sums   = cursor + NNODES;
    int*   blk_off    = blk_sums + SCAN_B;
    int*   src_sorted = blk_off + SCAN_B + 2;    // keep int4 alignment slack
    float* w_sorted   = (float*)(src_sorted + NEDGE);

    const int tpb = 256;
    const long nv4 = (long)NNODES * DIM / 4;
    const int ewBlocks = (int)((nv4 + tpb - 1) / tpb);          // 9375
    const int edgeBlocks = (NEDGE + tpb - 1) / tpb;             // 7813
    const int nodeWaveBlocks = (NNODES * 64 + tpb - 1) / tpb;   // 37500

    hipMemsetAsync(counts, 0, NNODES * sizeof(int), stream);

    init_kernel<<<ewBlocks, tpb, 0, stream>>>(eu, eit, buf0, out);

    // Build CSR by dst (parallel 3-phase scan)
    hist_kernel<<<edgeBlocks, tpb, 0, stream>>>(eidx, counts);
    blk_sum_kernel<<<SCAN_B, 256, 0, stream>>>(counts, blk_sums);
    blk_scan_kernel<<<1, 256, 0, stream>>>(blk_sums, blk_off);
    scan_apply_kernel<<<SCAN_B, 256, 0, stream>>>(counts, blk_off, row_start, cursor);
    fill_kernel<<<edgeBlocks, tpb, 0, stream>>>(eidx, ew, cursor, src_sorted, w_sorted);

    // layer 1: buf0 -> buf1 (fused relu)
    pull_kernel<<<nodeWaveBlocks, tpb, 0, stream>>>(row_start, src_sorted, w_sorted, buf0, buf1);
    // layer 2: buf1 -> buf2
    pull_kernel<<<nodeWaveBlocks, tpb, 0, stream>>>(row_start, src_sorted, w_sorted, buf1, buf2);

    // epilogue GEMM (sums the three layer embeddings on the fly)
    final_kernel<<<1024, tpb, 0, stream>>>(buf0, buf1, buf2, W, bias, out);
}

// Round 5
// 652.037 us; speedup vs baseline: 1.8895x; 1.8895x over previous
//
#include <hip/hip_runtime.h>

#define NUSERS 100000
#define NITEMS 50000
#define NNODES (NUSERS + NITEMS)
#define DIM 64
#define NEDGE 2000000
#define NI4 (NNODES / 4)            // 37500 int4 count-groups
#define SCAN_B ((NI4 + 255) / 256)  // 147 blocks
#define FT_ROWS 128                 // final-kernel tile rows
#define FT_BLOCKS ((NNODES + FT_ROWS - 1) / FT_ROWS)   // 1172

// ---------------------------------------------------------------------------
// init: buf0 = concat(emb_users, emb_items); also write the two
// pass-through output copies. float4 per thread.
// ---------------------------------------------------------------------------
__global__ void init_kernel(const float* __restrict__ eu, const float* __restrict__ eit,
                            float* __restrict__ buf0, float* __restrict__ out) {
    long i = (long)blockIdx.x * blockDim.x + threadIdx.x;      // float4 index
    const long total = (long)NNODES * DIM / 4;
    if (i >= total) return;
    const long ue = (long)NUSERS * DIM / 4;
    float4 v;
    if (i < ue) {
        v = ((const float4*)eu)[i];
        ((float4*)(out + (long)NUSERS * DIM))[i] = v;                          // users copy
    } else {
        long j = i - ue;
        v = ((const float4*)eit)[j];
        ((float4*)(out + (long)2 * NUSERS * DIM + (long)NITEMS * DIM))[j] = v; // items copy
    }
    ((float4*)buf0)[i] = v;
}

// ---------------------------------------------------------------------------
// CSR build step 1: histogram of dst. counts must be pre-zeroed.
// ---------------------------------------------------------------------------
__global__ void hist_kernel(const int* __restrict__ eidx, int* __restrict__ counts) {
    int e = blockIdx.x * blockDim.x + threadIdx.x;
    if (e < NEDGE) atomicAdd(&counts[eidx[NEDGE + e]], 1);
}

// ---------------------------------------------------------------------------
// CSR build step 2a: per-block sums (1024 counts per block via int4).
// ---------------------------------------------------------------------------
__global__ void blk_sum_kernel(const int* __restrict__ counts, int* __restrict__ blk_sums) {
    __shared__ int lds[256];
    int t = threadIdx.x;
    int i4 = blockIdx.x * 256 + t;
    int s = 0;
    if (i4 < NI4) {
        int4 c = ((const int4*)counts)[i4];
        s = c.x + c.y + c.z + c.w;
    }
    lds[t] = s;
    __syncthreads();
    for (int d = 128; d > 0; d >>= 1) {
        if (t < d) lds[t] += lds[t + d];
        __syncthreads();
    }
    if (t == 0) blk_sums[blockIdx.x] = lds[0];
}

// ---------------------------------------------------------------------------
// CSR build step 2b: exclusive scan of the SCAN_B block sums (single block).
// ---------------------------------------------------------------------------
__global__ void blk_scan_kernel(const int* __restrict__ blk_sums, int* __restrict__ blk_off) {
    __shared__ int lds[256];
    int t = threadIdx.x;
    int v = (t < SCAN_B) ? blk_sums[t] : 0;
    lds[t] = v;
    __syncthreads();
    for (int d = 1; d < 256; d <<= 1) {
        int u = (t >= d) ? lds[t - d] : 0;
        __syncthreads();
        lds[t] += u;
        __syncthreads();
    }
    if (t < SCAN_B) blk_off[t] = lds[t] - v;   // exclusive
}

// ---------------------------------------------------------------------------
// CSR build step 2c: local exclusive scan + block offset -> row_start, cursor.
// ---------------------------------------------------------------------------
__global__ void scan_apply_kernel(const int* __restrict__ counts, const int* __restrict__ blk_off,
                                  int* __restrict__ row_start, int* __restrict__ cursor) {
    __shared__ int lds[256];
    int t = threadIdx.x;
    int i4 = blockIdx.x * 256 + t;
    int4 c = make_int4(0, 0, 0, 0);
    if (i4 < NI4) c = ((const int4*)counts)[i4];
    int tsum = c.x + c.y + c.z + c.w;
    lds[t] = tsum;
    __syncthreads();
    for (int d = 1; d < 256; d <<= 1) {
        int u = (t >= d) ? lds[t - d] : 0;
        __syncthreads();
        lds[t] += u;
        __syncthreads();
    }
    if (i4 < NI4) {
        int base = blk_off[blockIdx.x] + lds[t] - tsum;   // exclusive across chunk
        int4 r;
        r.x = base;
        r.y = base + c.x;
        r.z = r.y + c.y;
        r.w = r.z + c.z;
        ((int4*)row_start)[i4] = r;
        ((int4*)cursor)[i4] = r;
    }
    if (blockIdx.x == 0 && t == 0) row_start[NNODES] = NEDGE;
}

// ---------------------------------------------------------------------------
// CSR build step 3: bucket edges by dst.
// ---------------------------------------------------------------------------
__global__ void fill_kernel(const int* __restrict__ eidx, const float* __restrict__ ew,
                            int* __restrict__ cursor, int* __restrict__ src_sorted,
                            float* __restrict__ w_sorted) {
    int e = blockIdx.x * blockDim.x + threadIdx.x;
    if (e >= NEDGE) return;
    int d = eidx[NEDGE + e];
    int pos = atomicAdd(&cursor[d], 1);
    src_sorted[pos] = eidx[e];
    w_sorted[pos] = ew[e];
}

// ---------------------------------------------------------------------------
// pull: one wave per dst node, lane = dim. No atomics; fused ReLU.
// ---------------------------------------------------------------------------
__global__ void pull_kernel(const int* __restrict__ row_start, const int* __restrict__ src_sorted,
                            const float* __restrict__ w_sorted, const float* __restrict__ in_emb,
                            float* __restrict__ out_emb) {
    int lane = threadIdx.x & 63;
    int n = (int)((blockIdx.x * (long)blockDim.x + threadIdx.x) >> 6);  // node = wave id
    if (n >= NNODES) return;
    int b = row_start[n];
    int e2 = row_start[n + 1];
    float s = 0.f;
    int i = b;
    for (; i + 1 < e2; i += 2) {
        int s0 = src_sorted[i], s1 = src_sorted[i + 1];
        float w0 = w_sorted[i], w1 = w_sorted[i + 1];
        float v0 = in_emb[(long)s0 * DIM + lane];
        float v1 = in_emb[(long)s1 * DIM + lane];
        s = fmaf(w0, v0, s);
        s = fmaf(w1, v1, s);
    }
    if (i < e2) {
        int s0 = src_sorted[i];
        float w0 = w_sorted[i];
        s = fmaf(w0, in_emb[(long)s0 * DIM + lane], s);
    }
    out_emb[(long)n * DIM + lane] = fmaxf(s, 0.f);
}

// ---------------------------------------------------------------------------
// epilogue GEMM, tile-staged:
//   stage: 128 rows of (e0+e1+e2) -> LDS via coalesced float4 loads
//   compute: lane j holds W row j in 64 VGPRs; rows broadcast from LDS via
//            ds_read_b128 (same-address -> conflict-free); 2 FMA chains.
//   out[i][j] = (a_i / 3) . W[j][:] + b[j], coalesced dword store per row.
// ---------------------------------------------------------------------------
__global__ __launch_bounds__(256)
void final_kernel(const float* __restrict__ e0, const float* __restrict__ e1,
                  const float* __restrict__ e2, const float* __restrict__ W,
                  const float* __restrict__ bias, float* __restrict__ out) {
    __shared__ float4 As4[FT_ROWS * 16];                 // 128 rows x 64 floats = 32 KB
    const int t = threadIdx.x;
    const int lane = t & 63;
    const int wv = t >> 6;
    const long R0 = (long)blockIdx.x * FT_ROWS;

    // W row for this lane -> 64 VGPRs (16 KB array, L1-resident after first block)
    float wreg[64];
#pragma unroll
    for (int k = 0; k < 16; ++k) {
        float4 wq = ((const float4*)(W + (long)lane * 64))[k];
        wreg[4 * k + 0] = wq.x; wreg[4 * k + 1] = wq.y;
        wreg[4 * k + 2] = wq.z; wreg[4 * k + 3] = wq.w;
    }
    float bj = bias[lane];

    // stage: 2048 float4s, 8 per thread, coalesced
    const float4* g0 = (const float4*)(e0 + R0 * DIM);
    const float4* g1 = (const float4*)(e1 + R0 * DIM);
    const float4* g2 = (const float4*)(e2 + R0 * DIM);
#pragma unroll
    for (int it = 0; it < 8; ++it) {
        int idx = it * 256 + t;                          // float4 index in tile
        if (R0 + (idx >> 4) < NNODES) {
            float4 v0 = g0[idx], v1 = g1[idx], v2 = g2[idx];
            float4 s;
            s.x = v0.x + v1.x + v2.x; s.y = v0.y + v1.y + v2.y;
            s.z = v0.z + v1.z + v2.z; s.w = v0.w + v1.w + v2.w;
            As4[idx] = s;
        }
    }
    __syncthreads();

    // compute: wave wv owns rows [32*wv, 32*wv+32)
#pragma unroll 4
    for (int r = 0; r < 32; ++r) {
        int tr = wv * 32 + r;
        long row = R0 + tr;
        if (row >= NNODES) break;                        // wave-uniform
        const float4* a = As4 + tr * 16;
        float s0 = 0.f, s1 = 0.f;
#pragma unroll
        for (int k = 0; k < 16; ++k) {
            float4 v = a[k];                             // LDS broadcast
            s0 = fmaf(v.x, wreg[4 * k + 0], s0);
            s1 = fmaf(v.y, wreg[4 * k + 1], s1);
            s0 = fmaf(v.z, wreg[4 * k + 2], s0);
            s1 = fmaf(v.w, wreg[4 * k + 3], s1);
        }
        float val = fmaf(s0 + s1, (1.0f / 3.0f), bj);
        long o = (row < NUSERS) ? row * DIM
                                : (long)2 * NUSERS * DIM + (row - NUSERS) * DIM;
        out[o + lane] = val;
    }
}

extern "C" void kernel_launch(void* const* d_in, const int* in_sizes, int n_in,
                              void* d_out, int out_size, void* d_ws, size_t ws_size,
                              hipStream_t stream) {
    const int*   eidx = (const int*)d_in[0];     // (2, E) int
    const float* ew   = (const float*)d_in[1];   // (E,)
    const float* eu   = (const float*)d_in[2];   // (NUSERS, 64)
    const float* eit  = (const float*)d_in[3];   // (NITEMS, 64)
    const float* W    = (const float*)d_in[4];   // (64, 64)
    const float* bias = (const float*)d_in[5];   // (64,)
    float* out = (float*)d_out;

    const size_t nfeat = (size_t)NNODES * DIM;   // 9.6M floats
    float* buf0 = (float*)d_ws;                  // emb_0 (input concat)
    float* buf1 = buf0 + nfeat;                  // emb_1
    float* buf2 = buf1 + nfeat;                  // emb_2
    int*   counts     = (int*)(buf2 + nfeat);
    int*   row_start  = counts + NNODES;         // NNODES+1 entries (+pad)
    int*   cursor     = row_start + NNODES + 4;  // 16B-aligned
    int*   blk_sums   = cursor + NNODES;
    int*   blk_off    = blk_sums + SCAN_B;
    int*   src_sorted = blk_off + SCAN_B + 2;
    float* w_sorted   = (float*)(src_sorted + NEDGE);

    const int tpb = 256;
    const long nv4 = (long)NNODES * DIM / 4;
    const int ewBlocks = (int)((nv4 + tpb - 1) / tpb);          // 9375
    const int edgeBlocks = (NEDGE + tpb - 1) / tpb;             // 7813
    const int nodeWaveBlocks = (NNODES * 64 + tpb - 1) / tpb;   // 37500

    hipMemsetAsync(counts, 0, NNODES * sizeof(int), stream);

    init_kernel<<<ewBlocks, tpb, 0, stream>>>(eu, eit, buf0, out);

    // Build CSR by dst (parallel 3-phase scan)
    hist_kernel<<<edgeBlocks, tpb, 0, stream>>>(eidx, counts);
    blk_sum_kernel<<<SCAN_B, 256, 0, stream>>>(counts, blk_sums);
    blk_scan_kernel<<<1, 256, 0, stream>>>(blk_sums, blk_off);
    scan_apply_kernel<<<SCAN_B, 256, 0, stream>>>(counts, blk_off, row_start, cursor);
    fill_kernel<<<edgeBlocks, tpb, 0, stream>>>(eidx, ew, cursor, src_sorted, w_sorted);

    // layer 1: buf0 -> buf1 (fused relu)
    pull_kernel<<<nodeWaveBlocks, tpb, 0, stream>>>(row_start, src_sorted, w_sorted, buf0, buf1);
    // layer 2: buf1 -> buf2
    pull_kernel<<<nodeWaveBlocks, tpb, 0, stream>>>(row_start, src_sorted, w_sorted, buf1, buf2);

    // epilogue GEMM (sums the three layer embeddings on the fly)
    final_kernel<<<FT_BLOCKS, tpb, 0, stream>>>(buf0, buf1, buf2, W, bias, out);
}

// Round 6
// 614.668 us; speedup vs baseline: 2.0044x; 1.0608x over previous
//
#include <hip/hip_runtime.h>

#define NUSERS 100000
#define NITEMS 50000
#define NNODES (NUSERS + NITEMS)
#define DIM 64
#define NEDGE 2000000
#define NI4 (NNODES / 4)            // 37500 int4 count-groups
#define SCAN_B ((NI4 + 255) / 256)  // 147 blocks
#define FT_ROWS 128                 // final-kernel tile rows
#define FT_BLOCKS ((NNODES + FT_ROWS - 1) / FT_ROWS)   // 1172

// ---------------------------------------------------------------------------
// init: buf0 = concat(emb_users, emb_items); also write the two
// pass-through output copies. float4 per thread.
// ---------------------------------------------------------------------------
__global__ void init_kernel(const float* __restrict__ eu, const float* __restrict__ eit,
                            float* __restrict__ buf0, float* __restrict__ out) {
    long i = (long)blockIdx.x * blockDim.x + threadIdx.x;      // float4 index
    const long total = (long)NNODES * DIM / 4;
    if (i >= total) return;
    const long ue = (long)NUSERS * DIM / 4;
    float4 v;
    if (i < ue) {
        v = ((const float4*)eu)[i];
        ((float4*)(out + (long)NUSERS * DIM))[i] = v;                          // users copy
    } else {
        long j = i - ue;
        v = ((const float4*)eit)[j];
        ((float4*)(out + (long)2 * NUSERS * DIM + (long)NITEMS * DIM))[j] = v; // items copy
    }
    ((float4*)buf0)[i] = v;
}

// ---------------------------------------------------------------------------
// CSR build step 1: histogram of dst. counts must be pre-zeroed.
// ---------------------------------------------------------------------------
__global__ void hist_kernel(const int* __restrict__ eidx, int* __restrict__ counts) {
    int e = blockIdx.x * blockDim.x + threadIdx.x;
    if (e < NEDGE) atomicAdd(&counts[eidx[NEDGE + e]], 1);
}

// ---------------------------------------------------------------------------
// CSR build step 2a: per-block sums (1024 counts per block via int4).
// ---------------------------------------------------------------------------
__global__ void blk_sum_kernel(const int* __restrict__ counts, int* __restrict__ blk_sums) {
    __shared__ int lds[256];
    int t = threadIdx.x;
    int i4 = blockIdx.x * 256 + t;
    int s = 0;
    if (i4 < NI4) {
        int4 c = ((const int4*)counts)[i4];
        s = c.x + c.y + c.z + c.w;
    }
    lds[t] = s;
    __syncthreads();
    for (int d = 128; d > 0; d >>= 1) {
        if (t < d) lds[t] += lds[t + d];
        __syncthreads();
    }
    if (t == 0) blk_sums[blockIdx.x] = lds[0];
}

// ---------------------------------------------------------------------------
// CSR build step 2b: exclusive scan of the SCAN_B block sums (single block).
// ---------------------------------------------------------------------------
__global__ void blk_scan_kernel(const int* __restrict__ blk_sums, int* __restrict__ blk_off) {
    __shared__ int lds[256];
    int t = threadIdx.x;
    int v = (t < SCAN_B) ? blk_sums[t] : 0;
    lds[t] = v;
    __syncthreads();
    for (int d = 1; d < 256; d <<= 1) {
        int u = (t >= d) ? lds[t - d] : 0;
        __syncthreads();
        lds[t] += u;
        __syncthreads();
    }
    if (t < SCAN_B) blk_off[t] = lds[t] - v;   // exclusive
}

// ---------------------------------------------------------------------------
// CSR build step 2c: local exclusive scan + block offset -> row_start, cursor.
// ---------------------------------------------------------------------------
__global__ void scan_apply_kernel(const int* __restrict__ counts, const int* __restrict__ blk_off,
                                  int* __restrict__ row_start, int* __restrict__ cursor) {
    __shared__ int lds[256];
    int t = threadIdx.x;
    int i4 = blockIdx.x * 256 + t;
    int4 c = make_int4(0, 0, 0, 0);
    if (i4 < NI4) c = ((const int4*)counts)[i4];
    int tsum = c.x + c.y + c.z + c.w;
    lds[t] = tsum;
    __syncthreads();
    for (int d = 1; d < 256; d <<= 1) {
        int u = (t >= d) ? lds[t - d] : 0;
        __syncthreads();
        lds[t] += u;
        __syncthreads();
    }
    if (i4 < NI4) {
        int base = blk_off[blockIdx.x] + lds[t] - tsum;   // exclusive across chunk
        int4 r;
        r.x = base;
        r.y = base + c.x;
        r.z = r.y + c.y;
        r.w = r.z + c.z;
        ((int4*)row_start)[i4] = r;
        ((int4*)cursor)[i4] = r;
    }
    if (blockIdx.x == 0 && t == 0) row_start[NNODES] = NEDGE;
}

// ---------------------------------------------------------------------------
// CSR build step 3: bucket edges by dst. Packed (src, w) record -> one 8B
// scattered store per edge (halves dirty-line traffic vs two 4B stores).
// ---------------------------------------------------------------------------
__global__ void fill_kernel(const int* __restrict__ eidx, const float* __restrict__ ew,
                            int* __restrict__ cursor, int2* __restrict__ edge_packed) {
    int e = blockIdx.x * blockDim.x + threadIdx.x;
    if (e >= NEDGE) return;
    int d = eidx[NEDGE + e];
    int s = eidx[e];
    float w = ew[e];
    int pos = atomicAdd(&cursor[d], 1);
    int2 rec;
    rec.x = s;
    rec.y = __float_as_int(w);
    edge_packed[pos] = rec;
}

// ---------------------------------------------------------------------------
// pull: one wave per dst node, lane = dim. No atomics; fused ReLU.
// Packed 8B edge records; 4-wide unroll, 2 independent accumulators.
// ---------------------------------------------------------------------------
__global__ void pull_kernel(const int* __restrict__ row_start,
                            const int2* __restrict__ edge_packed,
                            const float* __restrict__ in_emb,
                            float* __restrict__ out_emb) {
    int lane = threadIdx.x & 63;
    int n = (int)((blockIdx.x * (long)blockDim.x + threadIdx.x) >> 6);  // node = wave id
    if (n >= NNODES) return;
    int b = row_start[n];
    int e2 = row_start[n + 1];
    float sa = 0.f, sb = 0.f;
    int i = b;
    for (; i + 3 < e2; i += 4) {
        int2 r0 = edge_packed[i],     r1 = edge_packed[i + 1];
        int2 r2 = edge_packed[i + 2], r3 = edge_packed[i + 3];
        float v0 = in_emb[(long)r0.x * DIM + lane];
        float v1 = in_emb[(long)r1.x * DIM + lane];
        float v2 = in_emb[(long)r2.x * DIM + lane];
        float v3 = in_emb[(long)r3.x * DIM + lane];
        sa = fmaf(__int_as_float(r0.y), v0, sa);
        sb = fmaf(__int_as_float(r1.y), v1, sb);
        sa = fmaf(__int_as_float(r2.y), v2, sa);
        sb = fmaf(__int_as_float(r3.y), v3, sb);
    }
    for (; i < e2; ++i) {
        int2 r = edge_packed[i];
        sa = fmaf(__int_as_float(r.y), in_emb[(long)r.x * DIM + lane], sa);
    }
    out_emb[(long)n * DIM + lane] = fmaxf(sa + sb, 0.f);
}

// ---------------------------------------------------------------------------
// epilogue GEMM, tile-staged:
//   stage: 128 rows of (e0+e1+e2) -> LDS via coalesced float4 loads
//   compute: lane j holds W row j in 64 VGPRs; rows broadcast from LDS via
//            ds_read_b128 (same-address -> conflict-free); 2 FMA chains.
// ---------------------------------------------------------------------------
__global__ __launch_bounds__(256)
void final_kernel(const float* __restrict__ e0, const float* __restrict__ e1,
                  const float* __restrict__ e2, const float* __restrict__ W,
                  const float* __restrict__ bias, float* __restrict__ out) {
    __shared__ float4 As4[FT_ROWS * 16];                 // 128 rows x 64 floats = 32 KB
    const int t = threadIdx.x;
    const int lane = t & 63;
    const int wv = t >> 6;
    const long R0 = (long)blockIdx.x * FT_ROWS;

    float wreg[64];
#pragma unroll
    for (int k = 0; k < 16; ++k) {
        float4 wq = ((const float4*)(W + (long)lane * 64))[k];
        wreg[4 * k + 0] = wq.x; wreg[4 * k + 1] = wq.y;
        wreg[4 * k + 2] = wq.z; wreg[4 * k + 3] = wq.w;
    }
    float bj = bias[lane];

    const float4* g0 = (const float4*)(e0 + R0 * DIM);
    const float4* g1 = (const float4*)(e1 + R0 * DIM);
    const float4* g2 = (const float4*)(e2 + R0 * DIM);
#pragma unroll
    for (int it = 0; it < 8; ++it) {
        int idx = it * 256 + t;                          // float4 index in tile
        if (R0 + (idx >> 4) < NNODES) {
            float4 v0 = g0[idx], v1 = g1[idx], v2 = g2[idx];
            float4 s;
            s.x = v0.x + v1.x + v2.x; s.y = v0.y + v1.y + v2.y;
            s.z = v0.z + v1.z + v2.z; s.w = v0.w + v1.w + v2.w;
            As4[idx] = s;
        }
    }
    __syncthreads();

#pragma unroll 4
    for (int r = 0; r < 32; ++r) {
        int tr = wv * 32 + r;
        long row = R0 + tr;
        if (row >= NNODES) break;                        // wave-uniform
        const float4* a = As4 + tr * 16;
        float s0 = 0.f, s1 = 0.f;
#pragma unroll
        for (int k = 0; k < 16; ++k) {
            float4 v = a[k];                             // LDS broadcast
            s0 = fmaf(v.x, wreg[4 * k + 0], s0);
            s1 = fmaf(v.y, wreg[4 * k + 1], s1);
            s0 = fmaf(v.z, wreg[4 * k + 2], s0);
            s1 = fmaf(v.w, wreg[4 * k + 3], s1);
        }
        float val = fmaf(s0 + s1, (1.0f / 3.0f), bj);
        long o = (row < NUSERS) ? row * DIM
                                : (long)2 * NUSERS * DIM + (row - NUSERS) * DIM;
        out[o + lane] = val;
    }
}

extern "C" void kernel_launch(void* const* d_in, const int* in_sizes, int n_in,
                              void* d_out, int out_size, void* d_ws, size_t ws_size,
                              hipStream_t stream) {
    const int*   eidx = (const int*)d_in[0];     // (2, E) int
    const float* ew   = (const float*)d_in[1];   // (E,)
    const float* eu   = (const float*)d_in[2];   // (NUSERS, 64)
    const float* eit  = (const float*)d_in[3];   // (NITEMS, 64)
    const float* W    = (const float*)d_in[4];   // (64, 64)
    const float* bias = (const float*)d_in[5];   // (64,)
    float* out = (float*)d_out;

    const size_t nfeat = (size_t)NNODES * DIM;   // 9.6M floats
    float* buf0 = (float*)d_ws;                  // emb_0 (input concat)
    float* buf1 = buf0 + nfeat;                  // emb_1
    float* buf2 = buf1 + nfeat;                  // emb_2
    int*   counts     = (int*)(buf2 + nfeat);
    int*   row_start  = counts + NNODES;         // NNODES+1 entries (+pad)
    int*   cursor     = row_start + NNODES + 4;  // 16B-aligned
    int*   blk_sums   = cursor + NNODES;
    int*   blk_off    = blk_sums + SCAN_B;
    int2*  edge_packed = (int2*)(blk_off + SCAN_B + 3);  // 8B-aligned

    const int tpb = 256;
    const long nv4 = (long)NNODES * DIM / 4;
    const int ewBlocks = (int)((nv4 + tpb - 1) / tpb);          // 9375
    const int edgeBlocks = (NEDGE + tpb - 1) / tpb;             // 7813
    const int nodeWaveBlocks = (NNODES * 64 + tpb - 1) / tpb;   // 37500

    hipMemsetAsync(counts, 0, NNODES * sizeof(int), stream);

    init_kernel<<<ewBlocks, tpb, 0, stream>>>(eu, eit, buf0, out);

    // Build CSR by dst (parallel 3-phase scan)
    hist_kernel<<<edgeBlocks, tpb, 0, stream>>>(eidx, counts);
    blk_sum_kernel<<<SCAN_B, 256, 0, stream>>>(counts, blk_sums);
    blk_scan_kernel<<<1, 256, 0, stream>>>(blk_sums, blk_off);
    scan_apply_kernel<<<SCAN_B, 256, 0, stream>>>(counts, blk_off, row_start, cursor);
    fill_kernel<<<edgeBlocks, tpb, 0, stream>>>(eidx, ew, cursor, edge_packed);

    // layer 1: buf0 -> buf1 (fused relu)
    pull_kernel<<<nodeWaveBlocks, tpb, 0, stream>>>(row_start, edge_packed, buf0, buf1);
    // layer 2: buf1 -> buf2
    pull_kernel<<<nodeWaveBlocks, tpb, 0, stream>>>(row_start, edge_packed, buf1, buf2);

    // epilogue GEMM (sums the three layer embeddings on the fly)
    final_kernel<<<FT_BLOCKS, tpb, 0, stream>>>(buf0, buf1, buf2, W, bias, out);
}